// Round 2
// 288.760 us; speedup vs baseline: 1.0021x; 1.0021x over previous
//
#include <hip/hip_runtime.h>

// Problem: x (B=8, C=3, T=32, H=256, W=256) fp32 ->
//   grayscale (0.2989, 0.587, 0.114) over C ->
//   8x8 non-overlapping blocks -> 2D DCT-II (norm=None): out = D @ G @ D^T
//   out (B, T, 1024, 8, 8) fp32.
//
// Memory-bound: 201 MB read + 67 MB write => ~43 us at 6.3 TB/s achievable.
//
// v2 (resubmit after infra failure): persistent 2048-WG grid, 4 strips/WG,
//     double-buffered LDS with register prefetch (async-STAGE split: issue
//     loads pre-compute, consume post-compute), D-row-k in regs, b128 D
//     reads, nontemporal global traffic.

#define TPB 256
typedef float f4 __attribute__((ext_vector_type(4)));

__global__ __launch_bounds__(TPB) void dct_gray_kernel(
    const float* __restrict__ x, float* __restrict__ out) {
  constexpr int T = 32, H = 256, W = 256;
  constexpr int NSTRIPS = 8192;          // B*T*(H/8)
  constexpr int GRID = 2048;
  constexpr int ITERS = NSTRIPS / GRID;  // 4

  __shared__ float g[2][8][256];  // 16 KB: double-buffered grayscale strip
  __shared__ float Dm[64];        // DCT matrix D[k][n]

  const int tid = threadIdx.x;

  // Build D[k][n] = 2*cos(pi*(2n+1)*k/16) once per WG (64 lanes)
  if (tid < 64) {
    const int kk = tid >> 3, nn = tid & 7;
    Dm[tid] = 2.0f * cosf(0.19634954084936207f * (float)((2 * nn + 1) * kk));
  }

  const float w0 = 0.2989f, w1 = 0.587f, w2 = 0.114f;
  const size_t cstride = (size_t)T * H * W;  // channel stride (floats)

  const int p = tid >> 3;  // block 0..31 within strip
  const int k = tid & 7;   // output row within block

  // Per-thread D row k in registers (strip-invariant; kills per-strip
  // scalar ds_reads on the stage-A path).
  float dk[8];
#pragma unroll
  for (int n = 0; n < 8; ++n)
    dk[n] = 2.0f * cosf(0.19634954084936207f * (float)((2 * n + 1) * k));

  // strip index -> global base offset of its first pixel row
  auto strip_base = [&](int sidx) -> size_t {
    const int bt = sidx >> 5;  // b*T + t
    const int hb = sidx & 31;  // block-row
    const int b = bt >> 5;
    const int t = bt & 31;
    return ((size_t)(b * 3) * T + (size_t)t) * (size_t)(H * W) +
           (size_t)hb * 8 * W;
  };

  // ---- Prologue: stage strip 0 into buffer 0 ----
  {
    const size_t base0 = strip_base(blockIdx.x);
    f4 A[2], B[2], C[2];
#pragma unroll
    for (int j = 0; j < 2; ++j) {
      const int i = tid + j * TPB;  // 0..511
      const size_t off =
          base0 + (size_t)(i >> 6) * W + (size_t)((i & 63) * 4);
      A[j] = __builtin_nontemporal_load((const f4*)(x + off));
      B[j] = __builtin_nontemporal_load((const f4*)(x + off + cstride));
      C[j] = __builtin_nontemporal_load((const f4*)(x + off + 2 * cstride));
    }
#pragma unroll
    for (int j = 0; j < 2; ++j) {
      const int i = tid + j * TPB;
      f4 gg = w0 * A[j] + w1 * B[j] + w2 * C[j];
      *(f4*)(&g[0][i >> 6][(i & 63) * 4]) = gg;
    }
  }
  __syncthreads();  // also covers Dm visibility

  // ---- Main loop over 4 strips, double-buffered ----
  for (int s = 0; s < ITERS; ++s) {
    const int cur = s & 1;
    const int sidx = blockIdx.x + s * GRID;

    // 1) Issue next strip's global loads into registers (latency hides
    //    under the DCT compute below; consumed after the stores).
    f4 A[2], B[2], C[2];
    const bool more = (s + 1 < ITERS);
    if (more) {
      const size_t basep = strip_base(blockIdx.x + (s + 1) * GRID);
#pragma unroll
      for (int j = 0; j < 2; ++j) {
        const int i = tid + j * TPB;
        const size_t off =
            basep + (size_t)(i >> 6) * W + (size_t)((i & 63) * 4);
        A[j] = __builtin_nontemporal_load((const f4*)(x + off));
        B[j] = __builtin_nontemporal_load((const f4*)(x + off + cstride));
        C[j] = __builtin_nontemporal_load((const f4*)(x + off + 2 * cstride));
      }
    }

    // 2) DCT of current strip.
    // Stage A: temp[m] = sum_n D[k][n] * g[n][p*8+m]
    f4 t0 = {0.f, 0.f, 0.f, 0.f}, t1 = {0.f, 0.f, 0.f, 0.f};
#pragma unroll
    for (int n = 0; n < 8; ++n) {
      const float dkn = dk[n];
      const f4 g0 = *(const f4*)(&g[cur][n][p * 8]);      // ds_read_b128
      const f4 g1 = *(const f4*)(&g[cur][n][p * 8 + 4]);  // 2-way alias: free
      t0 += dkn * g0;
      t1 += dkn * g1;
    }
    // Stage B: res[l] = sum_m temp[m] * D[l][m]  (b128 broadcast D reads)
    float res[8];
#pragma unroll
    for (int l = 0; l < 8; ++l) {
      const f4 d0 = *(const f4*)(&Dm[l * 8]);
      const f4 d1 = *(const f4*)(&Dm[l * 8 + 4]);
      res[l] = t0.x * d0.x + t0.y * d0.y + t0.z * d0.z + t0.w * d0.w +
               t1.x * d1.x + t1.y * d1.y + t1.z * d1.z + t1.w * d1.w;
    }

    // 3) Store: WG owns 2048 contiguous floats at sidx*2048; thread writes
    //    8 consecutive floats at tid*8. Nontemporal (write-once stream).
    float* o = out + (size_t)sidx * 2048 + (size_t)tid * 8;
    f4 v0 = {res[0], res[1], res[2], res[3]};
    f4 v1 = {res[4], res[5], res[6], res[7]};
    __builtin_nontemporal_store(v0, (f4*)o);
    __builtin_nontemporal_store(v1, (f4*)(o + 4));

    // 4) Consume prefetched regs: grayscale + stage into the other buffer.
    if (more) {
#pragma unroll
      for (int j = 0; j < 2; ++j) {
        const int i = tid + j * TPB;
        f4 gg = w0 * A[j] + w1 * B[j] + w2 * C[j];
        *(f4*)(&g[cur ^ 1][i >> 6][(i & 63) * 4]) = gg;
      }
    }
    __syncthreads();
  }
}

extern "C" void kernel_launch(void* const* d_in, const int* in_sizes, int n_in,
                              void* d_out, int out_size, void* d_ws,
                              size_t ws_size, hipStream_t stream) {
  const float* x = (const float*)d_in[0];
  float* out = (float*)d_out;
  dct_gray_kernel<<<2048, TPB, 0, stream>>>(x, out);
}